// Round 12
// baseline (784.402 us; speedup 1.0000x reference)
//
#include <hip/hip_runtime.h>
#include <hip/hip_bf16.h>
#include <cstdint>
#include <cstddef>

#define NPTS 2048
#define P 32
#define KNN_K 15
#define LRELU_NEG 0.2f
#define BN_EPS 1e-5f

__device__ __forceinline__ float lrelu(float x) { return x > 0.f ? x : LRELU_NEG * x; }

__device__ __forceinline__ unsigned short f2bf(float x) {      // RNE f32 -> bf16 bits
    union { float f; unsigned u; } uu; uu.f = x;
    unsigned r = uu.u + 0x7fffu + ((uu.u >> 16) & 1u);
    return (unsigned short)(r >> 16);
}
__device__ __forceinline__ float bf2f(unsigned short b) {
    union { unsigned u; float f; } uu; uu.u = ((unsigned)b) << 16;
    return uu.f;
}

typedef short bf16x8 __attribute__((ext_vector_type(8)));
typedef float f32x4  __attribute__((ext_vector_type(4)));

// ================= mega-pack: all weight transforms in one launch =================
__device__ __forceinline__ void edge_pack_body(int i, const float* __restrict__ W,
                                               unsigned short* __restrict__ wpk,
                                               int C, int O, int NCHUNK)
{
    const int TOTC = 2 * O, NTT = TOTC / 16;
    if (i >= C * TOTC) return;
    int j = i & 7, lane = (i >> 3) & 63, rest = i >> 9;
    int ntg = rest % NTT, kb = rest / NTT;
    int k = kb * 32 + (lane >> 4) * 8 + j;
    int col = ntg * 16 + (lane & 15);
    int O2C = TOTC / NCHUNK, OC = O / NCHUNK;
    int chunk = col / O2C, cl = col % O2C;
    float v;
    if (cl < OC) { int o = chunk * OC + cl; v = W[(size_t)o * 2 * C + k]; }
    else         { int o = chunk * OC + cl - OC; v = W[(size_t)o * 2 * C + C + k] - W[(size_t)o * 2 * C + k]; }
    unsigned short hi = f2bf(v);
    wpk[(size_t)rest * 1024 + lane * 8 + j] = hi;
    wpk[(size_t)rest * 1024 + 512 + lane * 8 + j] = f2bf(v - bf2f(hi));
}

__device__ __forceinline__ void wfc_pack_body(int i, const float* __restrict__ W,
                                              unsigned short* __restrict__ wpk,
                                              int Kk, int Nn, int NTT)
{
    if (i >= NTT * 16 * Kk) return;
    int j = i & 7, lane = (i >> 3) & 63, rest = i >> 9;
    int ntg = rest % NTT, kb = rest / NTT;
    int k = kb * 32 + (lane >> 4) * 8 + j;
    int col = ntg * 16 + (lane & 15);
    float v = (col < Nn) ? W[(size_t)col * Kk + k] : 0.f;
    unsigned short hi = f2bf(v);
    wpk[(size_t)rest * 1024 + lane * 8 + j] = hi;
    wpk[(size_t)rest * 1024 + 512 + lane * 8 + j] = f2bf(v - bf2f(hi));
}

__global__ __launch_bounds__(256) void pack_all_kernel(
    const float* __restrict__ W1, const float* __restrict__ W2,
    const float* __restrict__ W3, const float* __restrict__ W4,
    const float* __restrict__ W5, const float* __restrict__ Wl1,
    const float* __restrict__ Wl2, const float* __restrict__ Wl3,
    float* __restrict__ wt1,
    unsigned short* __restrict__ wpk2, unsigned short* __restrict__ wpk3,
    unsigned short* __restrict__ wpk4, unsigned short* __restrict__ w5pk,
    unsigned short* __restrict__ fc1pk, unsigned short* __restrict__ fc2pk,
    unsigned short* __restrict__ fc3pk)
{
    const int b = blockIdx.x, t = threadIdx.x;
    if (b < 2) {                               // W1 wcat f32: C=3, O=64
        int i = b * 256 + t;
        if (i < 3 * 128) {
            int c = i / 128, col = i % 128;
            float v;
            if (col < 64) v = W1[(size_t)col * 6 + c];
            else          v = W1[(size_t)(col - 64) * 6 + 3 + c] - W1[(size_t)(col - 64) * 6 + c];
            wt1[i] = v;
        }
    } else if (b < 34)   edge_pack_body((b - 2)    * 256 + t, W2, wpk2, 64, 64, 1);
    else if (b < 98)     edge_pack_body((b - 34)   * 256 + t, W3, wpk3, 64, 128, 1);
    else if (b < 354)    edge_pack_body((b - 98)   * 256 + t, W4, wpk4, 128, 256, 2);
    else if (b < 2402) {                       // W5: [1024][512] -> frag order
        int i = (b - 354) * 256 + t;
        if (i < (1 << 19)) {
            int j = i & 7, lane = (i >> 3) & 63, nt = (i >> 9) & 63, kb = i >> 15;
            int c = kb * 32 + (lane >> 4) * 8 + j;
            int o = nt * 16 + (lane & 15);
            float f = W5[(size_t)o * 512 + c];
            unsigned short hi = f2bf(f);
            size_t base = (size_t)(kb * 64 + nt) * 1024 + (size_t)lane * 8 + j;
            w5pk[base] = hi;
            w5pk[base + 512] = f2bf(f - bf2f(hi));
        }
    }
    else if (b < 6498)   wfc_pack_body((b - 2402) * 256 + t, Wl1, fc1pk, 2048, 512, 32);
    else if (b < 7010)   wfc_pack_body((b - 6498) * 256 + t, Wl2, fc2pk, 512, 256, 16);
    else                 wfc_pack_body((b - 7010) * 256 + t, Wl3, fc3pk, 256, 800, 52);
}

// ================= edge conv, f32 VALU path (block 1: C=3) — stats pass fuses KNN =================
template<int C, int O, int NCHUNK, bool OUT>
__global__ __launch_bounds__(256) void edge_pass_kernel(
    const float* __restrict__ xin, int cloudStride,
    const float* __restrict__ wt,
    unsigned char* idx,                            // written if !OUT, read if OUT
    const float* __restrict__ st,
    float* __restrict__ xcout,
    float* __restrict__ partS, float* __restrict__ partQ)
{
    constexpr int TOTC = 2 * O;
    constexpr int O2C = TOTC / NCHUNK;
    constexpr int OC  = O / NCHUNK;
    constexpr int TPC = (O2C >= 256) ? 1 : (256 / O2C);
    constexpr int CPT = (O2C > 256) ? (O2C / 256) : 1;
    constexpr int PP  = P / TPC;
    constexpr int QUADS = OC / 4;
    constexpr int PG    = 256 / QUADS;
    constexpr int PPq   = P / PG;
    const int n = blockIdx.x, t = threadIdx.x;

    __shared__ float xs[C][P];
    __shared__ alignas(16) float gh[P * O2C];
    __shared__ unsigned char idl[P * KNN_K];
    __shared__ float xx[P];

    const float* xp = xin + (size_t)n * cloudStride;
    for (int i = t; i < C * P; i += 256) xs[i / P][i % P] = xp[i];

    if constexpr (!OUT) {
        // fused KNN (bit-identical to the standalone knn kernel): pd aliased on gh
        float* pd = gh;                            // [P][P+1]
        __syncthreads();
        if (t < P) { float s = 0.f; for (int c = 0; c < C; ++c) { float v = xs[c][t]; s = fmaf(v, v, s); } xx[t] = s; }
        __syncthreads();
        for (int i = t; i < P * P; i += 256) {
            int p = i >> 5, q = i & 31;
            float d = 0.f;
            for (int c = 0; c < C; ++c) d = fmaf(xs[c][p], xs[c][q], d);
            pd[p * (P + 1) + q] = 2.f * d - xx[p] - xx[q];   // diag exactly 0
        }
        __syncthreads();
        if (t < P) {
            for (int j = 0; j < KNN_K; ++j) {
                float best = -INFINITY; int bq = 0;
                for (int q = 0; q < P; ++q) { float v = pd[t * (P + 1) + q]; if (v > best) { best = v; bq = q; } }
                idl[t * KNN_K + j] = (unsigned char)bq;
                idx[(size_t)n * (P * KNN_K) + t * KNN_K + j] = (unsigned char)bq;
                pd[t * (P + 1) + bq] = -INFINITY;
            }
        }
    } else {
        for (int i = t; i < P * KNN_K; i += 256) idl[i] = idx[(size_t)n * (P * KNN_K) + i];
    }

    const int col = (O2C >= 256) ? t : (t % O2C);
    const int p0  = ((O2C >= 256) ? 0 : (t / O2C)) * PP;
    const int q4  = t % QUADS;
    const int pg  = t / QUADS;
    const int p0q = pg * PPq;

    for (int chunk = 0; chunk < NCHUNK; ++chunk) {
        __syncthreads();
        {
            float acc[CPT][PP];
            #pragma unroll
            for (int j = 0; j < CPT; ++j)
                #pragma unroll
                for (int p = 0; p < PP; ++p) acc[j][p] = 0.f;
            for (int c = 0; c < C; ++c) {
                float w[CPT];
                #pragma unroll
                for (int j = 0; j < CPT; ++j) w[j] = wt[(size_t)c * TOTC + chunk * O2C + col + j * 256];
                #pragma unroll
                for (int p = 0; p < PP; ++p) {
                    float xv = xs[c][p0 + p];
                    #pragma unroll
                    for (int j = 0; j < CPT; ++j) acc[j][p] = fmaf(w[j], xv, acc[j][p]);
                }
            }
            #pragma unroll
            for (int j = 0; j < CPT; ++j)
                #pragma unroll
                for (int p = 0; p < PP; ++p) gh[(p0 + p) * O2C + col + j * 256] = acc[j][p];
        }
        __syncthreads();

        if constexpr (!OUT) {
            f32x4 ssum4 = (f32x4)0.f, ssq4 = (f32x4)0.f;
            #pragma unroll
            for (int p = 0; p < PPq; ++p) {
                const int pp = p0q + p;
                const f32x4 gv = *(const f32x4*)&gh[pp * O2C + OC + q4 * 4];
                #pragma unroll
                for (int k = 0; k < KNN_K; ++k) {
                    const int q = idl[pp * KNN_K + k];
                    f32x4 yv = *(const f32x4*)&gh[q * O2C + q4 * 4] + gv;
                    ssum4 += yv; ssq4 += yv * yv;
                }
            }
            __syncthreads();           // all gathers done; reuse gh as reduction scratch
            #pragma unroll
            for (int e = 0; e < 4; ++e) {
                gh[(q4 * 4 + e) * PG + pg] = ssum4[e];
                gh[OC * PG + (q4 * 4 + e) * PG + pg] = ssq4[e];
            }
            __syncthreads();
            if (t < OC) {
                float S = 0.f, Q = 0.f;
                #pragma unroll
                for (int j = 0; j < PG; ++j) { S += gh[t * PG + j]; Q += gh[OC * PG + t * PG + j]; }
                partS[(size_t)(chunk * OC + t) * 2048 + n] = S;
                partQ[(size_t)(chunk * OC + t) * 2048 + n] = Q;
            }
        } else {
            const f32x4 s4  = *(const f32x4*)&st[chunk * OC + q4 * 4];
            const f32x4 sh4 = *(const f32x4*)&st[1024 + chunk * OC + q4 * 4];
            f32x4 sgn, sa;
            #pragma unroll
            for (int e = 0; e < 4; ++e) { sgn[e] = (s4[e] >= 0.f) ? 1.f : -1.f; sa[e] = fabsf(s4[e]); }
            f32x4 res[PPq];
            #pragma unroll
            for (int p = 0; p < PPq; ++p) {
                const int pp = p0q + p;
                const f32x4 gv = *(const f32x4*)&gh[pp * O2C + OC + q4 * 4];
                f32x4 gvs = sgn * gv;              // exact (+-)
                f32x4 mz = (f32x4)(-INFINITY);
                #pragma unroll
                for (int k = 0; k < KNN_K; ++k) {
                    const int q = idl[pp * KNN_K + k];
                    const f32x4 h4 = *(const f32x4*)&gh[q * O2C + q4 * 4];
                    #pragma unroll
                    for (int e = 0; e < 4; ++e) mz[e] = fmaxf(mz[e], fmaf(sgn[e], h4[e], gvs[e]));
                }
                #pragma unroll
                for (int e = 0; e < 4; ++e)
                    res[p][e] = lrelu(fmaf(sa[e], mz[e], sh4[e]));   // == lrelu(s*sel+sh) bitwise
            }
            __syncthreads();           // all gh reads done
            #pragma unroll
            for (int p = 0; p < PPq; ++p)
                #pragma unroll
                for (int e = 0; e < 4; ++e)
                    gh[(q4 * 4 + e) * (P + 1) + p0q + p] = res[p][e];
            __syncthreads();
            for (int i = t; i < OC * P; i += 256)
                xcout[(size_t)n * (512 * P) + chunk * OC * P + i] = gh[(i / P) * (P + 1) + (i % P)];
        }
    }
}

// ================= edge conv via MFMA (blocks 2-4) — stats pass fuses KNN =================
template<int C, int O, bool OUT>
__global__ __launch_bounds__(256) void edge_mfma_kernel(
    const float* __restrict__ xin, int cloudStride,
    const unsigned short* __restrict__ wpk,
    unsigned char* idx,                            // written if !OUT, read if OUT
    const float* __restrict__ st,
    float* __restrict__ xcout,
    float* __restrict__ partS, float* __restrict__ partQ)
{
    constexpr int TOTC  = 2 * O;
    constexpr int O2C   = (TOTC > 256) ? 256 : TOTC;
    constexpr int NCHUNK= TOTC / O2C;
    constexpr int OC    = O2C / 2;
    constexpr int NTW   = O2C / 64;
    constexpr int KB    = C / 32;
    constexpr int NTT   = TOTC / 16;
    constexpr int AS    = C + 8;
    constexpr int GHS   = O2C + 4;
    constexpr int QUADS = OC / 4;
    constexpr int PG    = 256 / QUADS;
    constexpr int PPq   = P / PG;
    static_assert(P * GHS >= C * P + P * (P + 1), "pd+xs must fit in gh");
    static_assert(P * GHS >= 2 * OC * PG, "stats scratch must fit in gh");

    const int n = blockIdx.x, t = threadIdx.x;
    const int w = t >> 6, l = t & 63;
    const int lg = l >> 4, lm = l & 15;

    __shared__ unsigned short Ah[P * AS];
    __shared__ unsigned short Al[P * AS];
    __shared__ alignas(16) float gh[P * GHS];
    __shared__ unsigned char idl[P * KNN_K];
    __shared__ float xx[P];

    const float* xp = xin + (size_t)n * cloudStride;
    if constexpr (!OUT) {
        float* xsf = gh;                 // [C*P] f32, alias
        float* pd  = gh + C * P;         // [P][P+1], alias
        for (int i = t; i < C * P; i += 256) {
            int c = i / P, p = i % P;
            float v = xp[i];
            unsigned short hi = f2bf(v);
            Ah[p * AS + c] = hi;
            Al[p * AS + c] = f2bf(v - bf2f(hi));
            xsf[i] = v;
        }
        __syncthreads();
        if (t < P) { float s = 0.f; for (int c = 0; c < C; ++c) { float v = xsf[c * P + t]; s = fmaf(v, v, s); } xx[t] = s; }
        __syncthreads();
        for (int i = t; i < P * P; i += 256) {
            int p = i >> 5, q = i & 31;
            float d = 0.f;
            for (int c = 0; c < C; ++c) d = fmaf(xsf[c * P + p], xsf[c * P + q], d);
            pd[p * (P + 1) + q] = 2.f * d - xx[p] - xx[q];
        }
        __syncthreads();
        if (t < P) {
            for (int j = 0; j < KNN_K; ++j) {
                float best = -INFINITY; int bq = 0;
                for (int q = 0; q < P; ++q) { float v = pd[t * (P + 1) + q]; if (v > best) { best = v; bq = q; } }
                idl[t * KNN_K + j] = (unsigned char)bq;
                idx[(size_t)n * (P * KNN_K) + t * KNN_K + j] = (unsigned char)bq;
                pd[t * (P + 1) + bq] = -INFINITY;
            }
        }
        __syncthreads();                 // idl visible; xsf/pd dead
    } else {
        for (int i = t; i < C * P; i += 256) {
            int c = i / P, p = i % P;
            float v = xp[i];
            unsigned short hi = f2bf(v);
            Ah[p * AS + c] = hi;
            Al[p * AS + c] = f2bf(v - bf2f(hi));
        }
        for (int i = t; i < P * KNN_K; i += 256) idl[i] = idx[(size_t)n * (P * KNN_K) + i];
        __syncthreads();
    }

    const int q4  = t % QUADS;
    const int pg  = t / QUADS;
    const int p0q = pg * PPq;

    for (int chunk = 0; chunk < NCHUNK; ++chunk) {
        f32x4 acc[2][NTW];
        #pragma unroll
        for (int mt = 0; mt < 2; ++mt)
            #pragma unroll
            for (int nt = 0; nt < NTW; ++nt) acc[mt][nt] = (f32x4)0.f;

        #pragma unroll
        for (int kb = 0; kb < KB; ++kb) {
            bf16x8 a_h[2], a_l[2];
            #pragma unroll
            for (int mt = 0; mt < 2; ++mt) {
                int row = mt * 16 + lm;
                a_h[mt] = *(const bf16x8*)&Ah[row * AS + kb * 32 + lg * 8];
                a_l[mt] = *(const bf16x8*)&Al[row * AS + kb * 32 + lg * 8];
            }
            #pragma unroll
            for (int nt = 0; nt < NTW; ++nt) {
                int ntg = chunk * (O2C / 16) + w * NTW + nt;
                const unsigned short* bp = wpk + (size_t)(kb * NTT + ntg) * 1024 + (size_t)l * 8;
                bf16x8 Bh = *(const bf16x8*)bp;
                bf16x8 Bl = *(const bf16x8*)(bp + 512);
                #pragma unroll
                for (int mt = 0; mt < 2; ++mt) {
                    acc[mt][nt] = __builtin_amdgcn_mfma_f32_16x16x32_bf16(a_h[mt], Bl, acc[mt][nt], 0, 0, 0);
                    acc[mt][nt] = __builtin_amdgcn_mfma_f32_16x16x32_bf16(a_l[mt], Bh, acc[mt][nt], 0, 0, 0);
                    acc[mt][nt] = __builtin_amdgcn_mfma_f32_16x16x32_bf16(a_h[mt], Bh, acc[mt][nt], 0, 0, 0);
                }
            }
        }
        __syncthreads();   // prev chunk's gh consumers done
        // scatter C frags: row = mt*16 + lg*4 + r, col = (w*NTW+nt)*16 + lm  [m89 mapping]
        #pragma unroll
        for (int mt = 0; mt < 2; ++mt)
            #pragma unroll
            for (int nt = 0; nt < NTW; ++nt) {
                int colb = (w * NTW + nt) * 16 + lm;
                #pragma unroll
                for (int r = 0; r < 4; ++r)
                    gh[(mt * 16 + lg * 4 + r) * GHS + colb] = acc[mt][nt][r];
            }
        __syncthreads();

        if constexpr (!OUT) {
            f32x4 ssum4 = (f32x4)0.f, ssq4 = (f32x4)0.f;
            #pragma unroll
            for (int p = 0; p < PPq; ++p) {
                const int pp = p0q + p;
                const f32x4 gv = *(const f32x4*)&gh[pp * GHS + OC + q4 * 4];
                #pragma unroll
                for (int k = 0; k < KNN_K; ++k) {
                    const int q = idl[pp * KNN_K + k];
                    f32x4 yv = *(const f32x4*)&gh[q * GHS + q4 * 4] + gv;
                    ssum4 += yv; ssq4 += yv * yv;
                }
            }
            __syncthreads();           // all gathers done; reuse gh as reduction scratch
            #pragma unroll
            for (int e = 0; e < 4; ++e) {
                gh[(q4 * 4 + e) * PG + pg] = ssum4[e];
                gh[OC * PG + (q4 * 4 + e) * PG + pg] = ssq4[e];
            }
            __syncthreads();
            if (t < OC) {
                float S = 0.f, Q = 0.f;
                #pragma unroll
                for (int j = 0; j < PG; ++j) { S += gh[t * PG + j]; Q += gh[OC * PG + t * PG + j]; }
                partS[(size_t)(chunk * OC + t) * 2048 + n] = S;
                partQ[(size_t)(chunk * OC + t) * 2048 + n] = Q;
            }
        } else {
            const f32x4 s4  = *(const f32x4*)&st[chunk * OC + q4 * 4];
            const f32x4 sh4 = *(const f32x4*)&st[1024 + chunk * OC + q4 * 4];
            f32x4 sgn, sa;
            #pragma unroll
            for (int e = 0; e < 4; ++e) { sgn[e] = (s4[e] >= 0.f) ? 1.f : -1.f; sa[e] = fabsf(s4[e]); }
            f32x4 res[PPq];
            #pragma unroll
            for (int p = 0; p < PPq; ++p) {
                const int pp = p0q + p;
                const f32x4 gv = *(const f32x4*)&gh[pp * GHS + OC + q4 * 4];
                f32x4 gvs = sgn * gv;              // exact (+-)
                f32x4 mz = (f32x4)(-INFINITY);
                #pragma unroll
                for (int k = 0; k < KNN_K; ++k) {
                    const int q = idl[pp * KNN_K + k];
                    const f32x4 h4 = *(const f32x4*)&gh[q * GHS + q4 * 4];
                    #pragma unroll
                    for (int e = 0; e < 4; ++e) mz[e] = fmaxf(mz[e], fmaf(sgn[e], h4[e], gvs[e]));
                }
                #pragma unroll
                for (int e = 0; e < 4; ++e)
                    res[p][e] = lrelu(fmaf(sa[e], mz[e], sh4[e]));   // == lrelu(s*sel+sh) bitwise
            }
            __syncthreads();           // all gh reads done
            #pragma unroll
            for (int p = 0; p < PPq; ++p)
                #pragma unroll
                for (int e = 0; e < 4; ++e)
                    gh[(q4 * 4 + e) * (P + 1) + p0q + p] = res[p][e];
            __syncthreads();
            for (int i = t; i < OC * P; i += 256)
                xcout[(size_t)n * (512 * P) + chunk * OC * P + i] = gh[(i / P) * (P + 1) + (i % P)];
        }
    }
}

// ================= reduce partials -> scale/shift per channel =================
__global__ __launch_bounds__(256) void reduce_stats_kernel(const float* __restrict__ partS,
                                                           const float* __restrict__ partQ,
                                                           const float* __restrict__ gamma,
                                                           const float* __restrict__ beta,
                                                           float* __restrict__ st, int nparts, float inv_count)
{
    const int o = blockIdx.x, t = threadIdx.x;
    __shared__ float rs[256], rq[256];
    float S = 0.f, Q = 0.f;
    for (int i = t; i < nparts; i += 256) { S += partS[(size_t)o * 2048 + i]; Q += partQ[(size_t)o * 2048 + i]; }
    rs[t] = S; rq[t] = Q; __syncthreads();
    for (int w = 128; w > 0; w >>= 1) { if (t < w) { rs[t] += rs[t + w]; rq[t] += rq[t + w]; } __syncthreads(); }
    if (t == 0) {
        float m = rs[0] * inv_count;
        float v = fmaxf(rq[0] * inv_count - m * m, 0.f);
        float s = gamma[o] * rsqrtf(v + BN_EPS);
        st[o] = s;
        st[1024 + o] = fmaf(-m, s, beta[o]);
    }
}

// ================= conv5 single pass: 1024 thr / 16 waves (acc 64 regs -> 4 waves/SIMD) =================
// A single-bf16, B hi/lo 2-term; T14 load/MFMA/commit order. Same arithmetic as 512-thr version.
__global__ __launch_bounds__(1024) void conv5_store_kernel(
    const float* xc, const unsigned short* __restrict__ wpack,
    unsigned short* y5,
    float* __restrict__ partS, float* __restrict__ partQ)
{
    const int b = blockIdx.x;
    const int t = threadIdx.x;
    const int w = t >> 6, l = t & 63;        // w: 0..15, each wave owns 4 ntg
    const int lg = l >> 4, lm = l & 15;

    __shared__ unsigned short Ah[2][64][40];

    f32x4 acc[4][4];                          // [mt][nt] = 64 VGPRs
    #pragma unroll
    for (int mt = 0; mt < 4; ++mt)
        #pragma unroll
        for (int nt = 0; nt < 4; ++nt) acc[mt][nt] = (f32x4)0.f;

    const float* xbase = xc + (size_t)(b * 2) * (512 * P);

    const int sp4    = t & 7;
    const int schalf = (t >> 3) & 15;
    const int scloud = (t >> 7) & 1;
    const bool sact  = t < 256;               // 4 of 16 waves stage; rest pure-MFMA

    float4 v0, v1;                            // staging registers (T14: load early, commit late)
    auto loadv = [&](int kb) {
        if (sact) {
            const float* src = xbase + (size_t)scloud * (512 * P)
                             + (size_t)(kb * 32 + 2 * schalf) * P + sp4 * 4;
            v0 = *(const float4*)src;
            v1 = *(const float4*)(src + P);
        }
    };
    auto commit = [&](int buf) {
        if (sact) {
            const int r0 = scloud * 32 + sp4 * 4;
            #pragma unroll
            for (int e = 0; e < 4; ++e) {
                unsigned short h0 = f2bf((&v0.x)[e]), h1 = f2bf((&v1.x)[e]);
                *(unsigned*)&Ah[buf][r0 + e][2 * schalf] = (unsigned)h0 | ((unsigned)h1 << 16);
            }
        }
    };

    loadv(0); commit(0);
    int cur = 0;
    for (int kb = 0; kb < 16; ++kb) {
        __syncthreads();                     // buf[cur] visible; prev reads of buf[cur^1] done
        if (kb + 1 < 16) loadv(kb + 1);      // issue global loads; latency hides under MFMA

        bf16x8 a_h[4];
        #pragma unroll
        for (int mt = 0; mt < 4; ++mt)
            a_h[mt] = *(const bf16x8*)&Ah[cur][mt * 16 + lm][lg * 8];
        #pragma unroll
        for (int nt = 0; nt < 4; ++nt) {
            const int ntg = w * 4 + nt;
            const unsigned short* bp = wpack + (size_t)(kb * 64 + ntg) * 1024 + (size_t)l * 8;
            bf16x8 Bh = *(const bf16x8*)bp;
            bf16x8 Bl = *(const bf16x8*)(bp + 512);
            #pragma unroll
            for (int mt = 0; mt < 4; ++mt) {
                acc[mt][nt] = __builtin_amdgcn_mfma_f32_16x16x32_bf16(a_h[mt], Bl, acc[mt][nt], 0, 0, 0);
                acc[mt][nt] = __builtin_amdgcn_mfma_f32_16x16x32_bf16(a_h[mt], Bh, acc[mt][nt], 0, 0, 0);
            }
        }
        if (kb + 1 < 16) commit(cur ^ 1);    // convert + ds_write after MFMA (other buffer)
        cur ^= 1;
    }
    __syncthreads();   // all xc reads complete before in-place overwrite

    #pragma unroll
    for (int nt = 0; nt < 4; ++nt) {
        const int ntg = w * 4 + nt;
        float s = 0.f, q = 0.f;
        #pragma unroll
        for (int mt = 0; mt < 4; ++mt)
            #pragma unroll
            for (int r = 0; r < 4; ++r) { float v = acc[mt][nt][r]; s += v; q = fmaf(v, v, q); }
        s += __shfl_xor(s, 16); q += __shfl_xor(q, 16);
        s += __shfl_xor(s, 32); q += __shfl_xor(q, 32);
        if (l < 16) {
            int o = ntg * 16 + lm;
            partS[(size_t)o * 2048 + b] = s;
            partQ[(size_t)o * 2048 + b] = q;
        }
        #pragma unroll
        for (int mt = 0; mt < 4; ++mt) {
            unsigned p0 = (unsigned)f2bf(acc[mt][nt][0]) | ((unsigned)f2bf(acc[mt][nt][1]) << 16);
            unsigned p1 = (unsigned)f2bf(acc[mt][nt][2]) | ((unsigned)f2bf(acc[mt][nt][3]) << 16);
            size_t off = (((size_t)b * 64 + ntg) * 4 + mt) * 64 + l;
            ((uint2*)y5)[off] = make_uint2(p0, p1);
        }
    }
}

// ================= conv5 finish: BN+lrelu+max/mean pool -> h =================
__global__ __launch_bounds__(512) void conv5_finish_kernel(
    const unsigned short* __restrict__ y5, const float* __restrict__ st, float* __restrict__ h)
{
    const int b = blockIdx.x, t = threadIdx.x;
    const int w = t >> 6, l = t & 63, lm = l & 15;
    #pragma unroll
    for (int nt = 0; nt < 8; ++nt) {
        const int o = w * 128 + nt * 16 + lm;
        const float sc = st[o], sh = st[1024 + o];
        #pragma unroll
        for (int cloud = 0; cloud < 2; ++cloud) {
            float mx = -INFINITY, sm = 0.f;
            #pragma unroll
            for (int half = 0; half < 2; ++half) {
                const int mt = cloud * 2 + half;
                uint2 pk = ((const uint2*)y5)[((((size_t)b * 8 + w) * 8 + nt) * 4 + mt) * 64 + l];
                #pragma unroll
                for (int r = 0; r < 4; ++r) {
                    unsigned word = (r < 2) ? pk.x : pk.y;
                    unsigned short bits = (unsigned short)((r & 1) ? (word >> 16) : (word & 0xffff));
                    float v = lrelu(fmaf(sc, bf2f(bits), sh));
                    mx = fmaxf(mx, v); sm += v;
                }
            }
            mx = fmaxf(mx, __shfl_xor(mx, 16)); sm += __shfl_xor(sm, 16);
            mx = fmaxf(mx, __shfl_xor(mx, 32)); sm += __shfl_xor(sm, 32);
            if (l < 16) {
                const int n = b * 2 + cloud;
                h[(size_t)n * 2048 + o] = mx;
                h[(size_t)n * 2048 + 1024 + o] = sm * (1.f / 32.f);
            }
        }
    }
}

// ================= FC GEMM via MFMA (fused BN-in / colstats-out) =================
template<bool BNIN, bool STATS>
__global__ __launch_bounds__(256) void gemm_mfma_nt(
    const float* __restrict__ A, const unsigned short* __restrict__ wpk,
    const float* __restrict__ stbn, const float* __restrict__ bias,
    float* __restrict__ Cc, float* __restrict__ partS, float* __restrict__ partQ,
    int Nn, int NTT, int Kk)
{
    const int o0 = blockIdx.x * 64;
    const int m0 = blockIdx.y * 64;
    const int t = threadIdx.x;
    const int w = t >> 6, l = t & 63;
    const int lg = l >> 4, lm = l & 15;

    __shared__ unsigned short Ah[2][64][40];
    __shared__ unsigned short Al[2][64][40];

    f32x4 acc[4];
    #pragma unroll
    for (int mt = 0; mt < 4; ++mt) acc[mt] = (f32x4)0.f;

    const int srow = t >> 3;
    const int sk4  = (t & 7) * 4;

    auto stage = [&](int kb, int buf) {
        const float* src = A + (size_t)(m0 + srow) * Kk + kb * 32 + sk4;
        float4 v0 = *(const float4*)src;
        float4 v1 = *(const float4*)(src + (size_t)32 * Kk);
        if (BNIN) {
            const float4 s4 = *(const float4*)(stbn + kb * 32 + sk4);
            const float4 t4 = *(const float4*)(stbn + 1024 + kb * 32 + sk4);
            #pragma unroll
            for (int e = 0; e < 4; ++e) {
                (&v0.x)[e] = lrelu(fmaf((&s4.x)[e], (&v0.x)[e], (&t4.x)[e]));
                (&v1.x)[e] = lrelu(fmaf((&s4.x)[e], (&v1.x)[e], (&t4.x)[e]));
            }
        }
        #pragma unroll
        for (int e = 0; e < 4; e += 2) {
            float a0 = (&v0.x)[e], a1 = (&v0.x)[e + 1];
            unsigned short h0 = f2bf(a0), h1 = f2bf(a1);
            *(unsigned*)&Ah[buf][srow][sk4 + e] = (unsigned)h0 | ((unsigned)h1 << 16);
            *(unsigned*)&Al[buf][srow][sk4 + e] =
                (unsigned)f2bf(a0 - bf2f(h0)) | ((unsigned)f2bf(a1 - bf2f(h1)) << 16);
            float b0 = (&v1.x)[e], b1 = (&v1.x)[e + 1];
            unsigned short g0 = f2bf(b0), g1 = f2bf(b1);
            *(unsigned*)&Ah[buf][srow + 32][sk4 + e] = (unsigned)g0 | ((unsigned)g1 << 16);
            *(unsigned*)&Al[buf][srow + 32][sk4 + e] =
                (unsigned)f2bf(b0 - bf2f(g0)) | ((unsigned)f2bf(b1 - bf2f(g1)) << 16);
        }
    };

    const int KB = Kk >> 5;
    stage(0, 0);
    int cur = 0;
    const int ntg = blockIdx.x * 4 + w;
    for (int kb = 0; kb < KB; ++kb) {
        __syncthreads();
        if (kb + 1 < KB) stage(kb + 1, cur ^ 1);
        bf16x8 a_h[4], a_l[4];
        #pragma unroll
        for (int mt = 0; mt < 4; ++mt) {
            a_h[mt] = *(const bf16x8*)&Ah[cur][mt * 16 + lm][lg * 8];
            a_l[mt] = *(const bf16x8*)&Al[cur][mt * 16 + lm][lg * 8];
        }
        const unsigned short* bp = wpk + ((size_t)kb * NTT + ntg) * 1024 + (size_t)l * 8;
        bf16x8 Bh = *(const bf16x8*)bp;
        bf16x8 Bl = *(const bf16x8*)(bp + 512);
        #pragma unroll
        for (int mt = 0; mt < 4; ++mt) {
            acc[mt] = __builtin_amdgcn_mfma_f32_16x16x32_bf16(a_h[mt], Bl, acc[mt], 0, 0, 0);
            acc[mt] = __builtin_amdgcn_mfma_f32_16x16x32_bf16(a_l[mt], Bh, acc[mt], 0, 0, 0);
            acc[mt] = __builtin_amdgcn_mfma_f32_16x16x32_bf16(a_h[mt], Bh, acc[mt], 0, 0, 0);
        }
        cur ^= 1;
    }

    const int col = o0 + w * 16 + lm;
    const bool cok = col < Nn;
    const float bv = (bias != nullptr && cok) ? bias[col] : 0.f;
    float s = 0.f, q = 0.f;
    #pragma unroll
    for (int mt = 0; mt < 4; ++mt) {
        #pragma unroll
        for (int r = 0; r < 4; ++r) {
            float v = acc[mt][r] + bv;
            if (STATS) { s += v; q = fmaf(v, v, q); }
            if (cok) Cc[(size_t)(m0 + mt * 16 + lg * 4 + r) * Nn + col] = v;
        }
    }
    if (STATS) {
        s += __shfl_xor(s, 16); q += __shfl_xor(q, 16);
        s += __shfl_xor(s, 32); q += __shfl_xor(q, 32);
        if (l < 16 && cok) {
            partS[(size_t)col * 2048 + blockIdx.y] = s;
            partQ[(size_t)col * 2048 + blockIdx.y] = q;
        }
    }
}

__global__ __launch_bounds__(256) void logsoftmax_kernel(float* __restrict__ out)
{
    const int n = blockIdx.x, t = threadIdx.x;
    float* row = out + (size_t)n * 800;
    __shared__ float red[256];
    float v[4];
    float mx = -INFINITY;
    #pragma unroll
    for (int j = 0; j < 4; ++j) {
        int i = t + j * 256;
        v[j] = (i < 800) ? row[i] : -INFINITY;
        mx = fmaxf(mx, v[j]);
    }
    red[t] = mx; __syncthreads();
    for (int w = 128; w > 0; w >>= 1) { if (t < w) red[t] = fmaxf(red[t], red[t + w]); __syncthreads(); }
    const float m = red[0]; __syncthreads();
    float s = 0.f;
    #pragma unroll
    for (int j = 0; j < 4; ++j) { int i = t + j * 256; if (i < 800) s += expf(v[j] - m); }
    red[t] = s; __syncthreads();
    for (int w = 128; w > 0; w >>= 1) { if (t < w) red[t] += red[t + w]; __syncthreads(); }
    const float lg = m + logf(red[0]);
    #pragma unroll
    for (int j = 0; j < 4; ++j) { int i = t + j * 256; if (i < 800) row[i] = v[j] - lg; }
}

extern "C" void kernel_launch(void* const* d_in, const int* in_sizes, int n_in,
                              void* d_out, int out_size, void* d_ws, size_t ws_size,
                              hipStream_t stream)
{
    (void)in_sizes; (void)n_in; (void)out_size; (void)ws_size;
    const float* x   = (const float*)d_in[0];
    const float* W1  = (const float*)d_in[2];
    const float* g1  = (const float*)d_in[3];
    const float* b1  = (const float*)d_in[4];
    const float* W2  = (const float*)d_in[5];
    const float* g2  = (const float*)d_in[6];
    const float* b2  = (const float*)d_in[7];
    const float* W3  = (const float*)d_in[8];
    const float* g3  = (const float*)d_in[9];
    const float* b3  = (const float*)d_in[10];
    const float* W4  = (const float*)d_in[11];
    const float* g4  = (const float*)d_in[12];
    const float* b4  = (const float*)d_in[13];
    const float* W5  = (const float*)d_in[14];
    const float* g5  = (const float*)d_in[15];
    const float* b5  = (const float*)d_in[16];
    const float* Wl1 = (const float*)d_in[17];
    const float* g6  = (const float*)d_in[18];
    const float* b6  = (const float*)d_in[19];
    const float* Wl2 = (const float*)d_in[20];
    const float* bl2 = (const float*)d_in[21];
    const float* g7  = (const float*)d_in[22];
    const float* b7  = (const float*)d_in[23];
    const float* Wl3 = (const float*)d_in[24];
    const float* bl3 = (const float*)d_in[25];

    char* ws = (char*)d_ws;
    size_t off = 0;
    auto alloc = [&](size_t bytes) -> void* {
        void* p = ws + off; off += (bytes + 255) & ~(size_t)255; return p;
    };
    float*          xc    = (float*)alloc((size_t)NPTS * 512 * P * 4);        // 134.2 MB
    unsigned char*  idx   = (unsigned char*)alloc((size_t)NPTS * P * KNN_K);  // 0.98 MB
    float*          partS = (float*)alloc((size_t)1024 * 2048 * 4);           // 8.4 MB
    float*          partQ = (float*)alloc((size_t)1024 * 2048 * 4);           // 8.4 MB
    float*          st    = (float*)alloc(2048 * 4);
    float*          wt1   = (float*)alloc(3 * 128 * 4);                       // block-1 wcat f32
    unsigned short* wpk2  = (unsigned short*)alloc((size_t)2 * 64 * 128 * 2);  // 32 KB
    unsigned short* wpk3  = (unsigned short*)alloc((size_t)2 * 64 * 256 * 2);  // 64 KB
    unsigned short* wpk4  = (unsigned short*)alloc((size_t)2 * 128 * 512 * 2); // 256 KB
    unsigned short* w5pk  = (unsigned short*)alloc((size_t)2 * 512 * 1024 * 2);// 2 MB
    unsigned short* fc1pk = (unsigned short*)alloc((size_t)2 * 512 * 2048 * 2);// 4 MB
    unsigned short* fc2pk = (unsigned short*)alloc((size_t)2 * 256 * 512 * 2); // 0.5 MB
    unsigned short* fc3pk = (unsigned short*)alloc((size_t)2 * 832 * 256 * 2); // 0.83 MB
    float*          h     = (float*)alloc((size_t)2048 * 2048 * 4);           // 16.8 MB
    float*          h1p   = (float*)alloc((size_t)2048 * 512 * 4);            // 4.2 MB
    unsigned short* y5 = (unsigned short*)xc;   // in-place
    float* h2p = h + 1048576;                   // h dead after FC1 gemm

    const float inv_edge = 1.f / (float)(NPTS * P * KNN_K);

    // ---- all weight packs, one launch ----
    pack_all_kernel<<<7842, 256, 0, stream>>>(W1, W2, W3, W4, W5, Wl1, Wl2, Wl3,
                                              wt1, wpk2, wpk3, wpk4, w5pk, fc1pk, fc2pk, fc3pk);

    // ---- edge block 1: x(C=3) -> O=64 (xc ch 0..63), f32 path, knn fused in stats ----
    edge_pass_kernel<3, 64, 1, false><<<NPTS, 256, 0, stream>>>(x, 3 * P, wt1, idx, nullptr, nullptr, partS, partQ);
    reduce_stats_kernel<<<64, 256, 0, stream>>>(partS, partQ, g1, b1, st, 2048, inv_edge);
    edge_pass_kernel<3, 64, 1, true><<<NPTS, 256, 0, stream>>>(x, 3 * P, wt1, idx, st, xc + 0 * P, nullptr, nullptr);

    // ---- edge block 2: xc ch 0..63 -> O=64 (ch 64..127), MFMA, knn fused ----
    edge_mfma_kernel<64, 64, false><<<NPTS, 256, 0, stream>>>(xc, 512 * P, wpk2, idx, nullptr, nullptr, partS, partQ);
    reduce_stats_kernel<<<64, 256, 0, stream>>>(partS, partQ, g2, b2, st, 2048, inv_edge);
    edge_mfma_kernel<64, 64, true><<<NPTS, 256, 0, stream>>>(xc, 512 * P, wpk2, idx, st, xc + 64 * P, nullptr, nullptr);

    // ---- edge block 3: xc ch 64..127 -> O=128 (ch 128..255), MFMA, knn fused ----
    edge_mfma_kernel<64, 128, false><<<NPTS, 256, 0, stream>>>(xc + 64 * P, 512 * P, wpk3, idx, nullptr, nullptr, partS, partQ);
    reduce_stats_kernel<<<128, 256, 0, stream>>>(partS, partQ, g3, b3, st, 2048, inv_edge);
    edge_mfma_kernel<64, 128, true><<<NPTS, 256, 0, stream>>>(xc + 64 * P, 512 * P, wpk3, idx, st, xc + 128 * P, nullptr, nullptr);

    // ---- edge block 4: xc ch 128..255 -> O=256 (ch 256..511), MFMA, knn fused ----
    edge_mfma_kernel<128, 256, false><<<NPTS, 256, 0, stream>>>(xc + 128 * P, 512 * P, wpk4, idx, nullptr, nullptr, partS, partQ);
    reduce_stats_kernel<<<256, 256, 0, stream>>>(partS, partQ, g4, b4, st, 2048, inv_edge);
    edge_mfma_kernel<128, 256, true><<<NPTS, 256, 0, stream>>>(xc + 128 * P, 512 * P, wpk4, idx, st, xc + 256 * P, nullptr, nullptr);

    // ---- stage 5 via MFMA, single GEMM pass (16 waves): stats + y5 in place; then BN+pool ----
    conv5_store_kernel<<<1024, 1024, 0, stream>>>(xc, w5pk, y5, partS, partQ);
    reduce_stats_kernel<<<1024, 256, 0, stream>>>(partS, partQ, g5, b5, st, 1024, 1.f / 65536.f);
    conv5_finish_kernel<<<1024, 512, 0, stream>>>(y5, st, h);

    // ---- FC head (MFMA, fused colstats + BN-in-stage) ----
    gemm_mfma_nt<false, true><<<dim3(8, 32), 256, 0, stream>>>(h, fc1pk, nullptr, nullptr, h1p, partS, partQ, 512, 32, 2048);
    reduce_stats_kernel<<<512, 256, 0, stream>>>(partS, partQ, g6, b6, st, 32, 1.f / 2048.f);

    gemm_mfma_nt<true, true><<<dim3(4, 32), 256, 0, stream>>>(h1p, fc2pk, st, bl2, h2p, partS, partQ, 256, 16, 512);
    reduce_stats_kernel<<<256, 256, 0, stream>>>(partS, partQ, g7, b7, st, 32, 1.f / 2048.f);

    gemm_mfma_nt<true, false><<<dim3(13, 32), 256, 0, stream>>>(h2p, fc3pk, st, bl3, (float*)d_out, nullptr, nullptr, 800, 52, 256);

    logsoftmax_kernel<<<NPTS, 256, 0, stream>>>((float*)d_out);
}